// Round 14
// baseline (1290.875 us; speedup 1.0000x reference)
//
#include <hip/hip_runtime.h>

#define BB 64      // batch
#define DD 512     // d_model = d_state = d_att
#define TT 32      // steps

__device__ __forceinline__ float dot4(const float4 a, const float4 b) {
  return a.x * b.x + a.y * b.y + a.z * b.z + a.w * b.w;
}

// write-through (agent-scope) scalar store: recurrent-state writes visible at the LLC.
__device__ __forceinline__ void cst(float* p, float v) {
  __hip_atomic_store(p, v, __ATOMIC_RELAXED, __HIP_MEMORY_SCOPE_AGENT);
}

// ---------------------------------------------------------------- setup: everything before the loop, one launch
__global__ __launch_bounds__(256) void setup_k(
    const float* __restrict__ wq, const float* __restrict__ bq,
    const float* __restrict__ wk, const float* __restrict__ bk,
    const float* __restrict__ tok, const float* __restrict__ grep,
    const float* __restrict__ w_ih, const float* __restrict__ b_ih,
    const float* __restrict__ w_init, const float* __restrict__ b_init,
    const float* __restrict__ w_loc, const float* __restrict__ b_loc,
    float* __restrict__ kqb, float* __restrict__ cbn, float* __restrict__ gig,
    float* __restrict__ sbuf, float* __restrict__ locg,
    float* __restrict__ aqkp, unsigned* __restrict__ bar) {
  __shared__ __align__(16) float As[16][132];
  __shared__ __align__(16) float Bs[16][68];
  const int blk = blockIdx.x, tid = threadIdx.x;

  if (blk < 128) {
    // Aqk[e,m] split-K partial: C[e,m] = sum_{a in z-chunk} wq[a,e]*wk[a,m]
    const int tx = tid & 15, ty = tid >> 4;
    const int m0 = (blk & 3) * 128, n0 = ((blk >> 2) & 7) * 64, zz = blk >> 5;
    float acc[8][4];
#pragma unroll
    for (int i = 0; i < 8; ++i)
#pragma unroll
      for (int j = 0; j < 4; ++j) acc[i][j] = 0.f;
    for (int k0 = zz * 128; k0 < zz * 128 + 128; k0 += 16) {
      {
        const int kk = tid >> 4, mseg = tid & 15;
        const float* ap = wq + (long)(k0 + kk) * 512 + m0 + mseg * 8;
        *(float4*)&As[kk][mseg * 8] = *(const float4*)ap;
        *(float4*)&As[kk][mseg * 8 + 4] = *(const float4*)(ap + 4);
      }
      {
        const int kk = tid >> 4, nq = tid & 15;
        *(float4*)&Bs[kk][nq * 4] = *(const float4*)(wk + (long)(k0 + kk) * 512 + n0 + nq * 4);
      }
      __syncthreads();
#pragma unroll
      for (int kk = 0; kk < 16; ++kk) {
        const float4 a0 = *(const float4*)&As[kk][ty * 8];
        const float4 a1 = *(const float4*)&As[kk][ty * 8 + 4];
        const float4 b0 = *(const float4*)&Bs[kk][tx * 4];
        const float am[8] = {a0.x, a0.y, a0.z, a0.w, a1.x, a1.y, a1.z, a1.w};
#pragma unroll
        for (int i = 0; i < 8; ++i) {
          acc[i][0] += am[i] * b0.x; acc[i][1] += am[i] * b0.y;
          acc[i][2] += am[i] * b0.z; acc[i][3] += am[i] * b0.w;
        }
      }
      __syncthreads();
    }
    float* Ce = aqkp + (long)zz * 262144;
#pragma unroll
    for (int i = 0; i < 8; ++i) {
      const int m = m0 + ty * 8 + i;
      *(float4*)&Ce[(long)m * 512 + n0 + tx * 4] =
          make_float4(acc[i][0], acc[i][1], acc[i][2], acc[i][3]);
    }
  } else if (blk < 130) {
    const int d = (blk - 128) * 256 + tid;
    float s = 0.f;
    for (int e = 0; e < DD; ++e) s += wq[e * DD + d] * bk[e];
    kqb[d] = s;
  } else if (blk < 146) {
    // cbn[m] = tok[m,:].wkbq + bqbk ; wkbq/bqbk recomputed locally
    float* wkb = &As[0][0];            // 512 floats
    float* red = &Bs[0][0];            // 256 floats
    for (int k = tid; k < 512; k += 256) {
      float s = 0.f;
      for (int e = 0; e < DD; ++e) s += bq[e] * wk[e * DD + k];
      wkb[k] = s;
    }
    red[tid] = bq[tid] * bk[tid] + bq[tid + 256] * bk[tid + 256];
    __syncthreads();
    for (int s2 = 128; s2; s2 >>= 1) {
      if (tid < s2) red[tid] += red[tid + s2];
      __syncthreads();
    }
    const float bqbk = red[0];
    const int m = (blk - 130) * 256 + tid;
    const float* tr = tok + (long)m * 512;
    float acc = bqbk;
    for (int e = 0; e < 512; e += 8) {
      acc += dot4(*(const float4*)(tr + e), *(const float4*)(wkb + e));
      acc += dot4(*(const float4*)(tr + e + 4), *(const float4*)(wkb + e + 4));
    }
    cbn[m] = acc;
  } else if (blk < 170) {
    // gig[b,o] = grep[b,:].w_ih[o,512:1024] + b_ih[o]
    const int o = (blk - 146) * 64 + (tid & 63);
    const int b0 = (tid >> 6) * 16;
    float acc[16];
#pragma unroll
    for (int i = 0; i < 16; ++i) acc[i] = 0.f;
    const float* wr = w_ih + (long)o * 1024 + 512;
    for (int e = 0; e < 512; e += 4) {
      const float4 w4 = *(const float4*)(wr + e);
#pragma unroll
      for (int i = 0; i < 16; ++i)
        acc[i] += dot4(*(const float4*)(grep + (long)(b0 + i) * 512 + e), w4);
    }
    const float bi = b_ih[o];
#pragma unroll
    for (int i = 0; i < 16; ++i)
      gig[(long)(b0 + i) * 1536 + o] = acc[i] + bi;
  } else if (blk < 178) {
    // s0[b,d] = tanh(grep[b,:].w_init[d,:] + b_init[d]) -> sbuf slot 0
    const int d = (blk - 170) * 64 + (tid & 63);
    const int b0 = (tid >> 6) * 16;
    float acc[16];
#pragma unroll
    for (int i = 0; i < 16; ++i) acc[i] = 0.f;
    const float* wr = w_init + (long)d * 512;
    for (int e = 0; e < 512; e += 4) {
      const float4 w4 = *(const float4*)(wr + e);
#pragma unroll
      for (int i = 0; i < 16; ++i)
        acc[i] += dot4(*(const float4*)(grep + (long)(b0 + i) * 512 + e), w4);
    }
    const float bi = b_init[d];
#pragma unroll
    for (int i = 0; i < 16; ++i)
      sbuf[(long)(b0 + i) * 512 + d] = tanhf(acc[i] + bi);
  } else if (blk == 178) {
    // locg[b,j] = grep[b,:].w_loc[j,1024:1536] + b_loc[j]
    if (tid < 128) {
      const int b = tid >> 1, j = tid & 1;
      const float* wr = w_loc + (long)j * 1536 + 1024;
      const float* gr = grep + (long)b * 512;
      float acc = b_loc[j];
      for (int e = 0; e < 512; e += 4)
        acc += dot4(*(const float4*)(gr + e), *(const float4*)(wr + e));
      locg[b * 2 + j] = acc;
    }
  } else {
    if (tid < 16)
      __hip_atomic_store(bar + tid * 64, 0u, __ATOMIC_RELAXED, __HIP_MEMORY_SCOPE_AGENT);
    __hip_atomic_store(bar + 1024 + tid * 32, 0u, __ATOMIC_RELAXED, __HIP_MEMORY_SCOPE_AGENT);
  }
}

// ---------------------------------------------------------------- dual big GEMM with inline Aqk combine (2 blocks/CU)
__global__ __launch_bounds__(256) void dual2_k(
    const float* __restrict__ A, const float* __restrict__ aqkp,
    const float* __restrict__ bias0, float* __restrict__ C0,
    const float* __restrict__ B1, const float* __restrict__ bias1, float* __restrict__ C1) {
  __shared__ __align__(16) float As[16][132];
  __shared__ __align__(16) float Bs[16][68];
  const int tid = threadIdx.x;
  const int tx = tid & 15, ty = tid >> 4;
  const int m0 = blockIdx.x * 128, n0 = blockIdx.y * 64;
  const int z = blockIdx.z;
  const float* bias = z ? bias1 : bias0;
  float* C = z ? C1 : C0;
  float acc[8][4];
#pragma unroll
  for (int i = 0; i < 8; ++i)
#pragma unroll
    for (int j = 0; j < 4; ++j) acc[i][j] = 0.f;

  for (int k0 = 0; k0 < 512; k0 += 16) {
    {
      const int row = tid >> 1, half = tid & 1;
      const float* ap = A + (long)(m0 + row) * 512 + k0 + half * 8;
      const float4 a0 = *(const float4*)ap;
      const float4 a1 = *(const float4*)(ap + 4);
      const int kb = half * 8;
      As[kb + 0][row] = a0.x; As[kb + 1][row] = a0.y; As[kb + 2][row] = a0.z; As[kb + 3][row] = a0.w;
      As[kb + 4][row] = a1.x; As[kb + 5][row] = a1.y; As[kb + 6][row] = a1.z; As[kb + 7][row] = a1.w;
    }
    {
      const int n = tid >> 2, q = tid & 3;
      float4 b0;
      if (z == 0) {
        const float* pb = aqkp + (long)(n0 + n) * 512 + k0 + q * 4;
        const float4 p0 = *(const float4*)pb;
        const float4 p1 = *(const float4*)(pb + 262144);
        const float4 p2 = *(const float4*)(pb + 524288);
        const float4 p3 = *(const float4*)(pb + 786432);
        b0 = make_float4(p0.x + p1.x + p2.x + p3.x, p0.y + p1.y + p2.y + p3.y,
                         p0.z + p1.z + p2.z + p3.z, p0.w + p1.w + p2.w + p3.w);
      } else {
        b0 = *(const float4*)(B1 + (long)(n0 + n) * 512 + k0 + q * 4);
      }
      Bs[q * 4 + 0][n] = b0.x; Bs[q * 4 + 1][n] = b0.y; Bs[q * 4 + 2][n] = b0.z; Bs[q * 4 + 3][n] = b0.w;
    }
    __syncthreads();
#pragma unroll
    for (int kk = 0; kk < 16; ++kk) {
      const float4 a0 = *(const float4*)&As[kk][ty * 8];
      const float4 a1 = *(const float4*)&As[kk][ty * 8 + 4];
      const float4 b0 = *(const float4*)&Bs[kk][tx * 4];
      const float am[8] = {a0.x, a0.y, a0.z, a0.w, a1.x, a1.y, a1.z, a1.w};
#pragma unroll
      for (int i = 0; i < 8; ++i) {
        acc[i][0] += am[i] * b0.x; acc[i][1] += am[i] * b0.y;
        acc[i][2] += am[i] * b0.z; acc[i][3] += am[i] * b0.w;
      }
    }
    __syncthreads();
  }
  const float4 bvv = *(const float4*)(bias + n0 + tx * 4);
#pragma unroll
  for (int i = 0; i < 8; ++i) {
    const int m = m0 + ty * 8 + i;
    float4 v = make_float4(acc[i][0] + bvv.x, acc[i][1] + bvv.y, acc[i][2] + bvv.z, acc[i][3] + bvv.w);
    *(float4*)&C[(long)m * 512 + n0 + tx * 4] = v;
  }
}

// ---------------------------------------------------------------- two-level grid barrier (256 blocks), contention-free polling
__device__ __forceinline__ void grid_barrier(unsigned* __restrict__ bar, unsigned gen) {
  __syncthreads();   // vmcnt(0) drain: prior write-through stores have reached the LLC
  const int blk = blockIdx.x, tid = threadIdx.x;
  unsigned* gctr = bar;
  unsigned* rel = bar + 1024;
  if (blk == 0) {
    if (tid == 0)
      __hip_atomic_fetch_add(gctr, 1u, __ATOMIC_RELAXED, __HIP_MEMORY_SCOPE_AGENT);
    if (tid < 16) {
      while (__hip_atomic_load(gctr + tid * 64, __ATOMIC_RELAXED, __HIP_MEMORY_SCOPE_AGENT) < gen * 16u)
        __builtin_amdgcn_s_sleep(1);
    }
    __syncthreads();
    __hip_atomic_store(rel + tid * 32, gen, __ATOMIC_RELAXED, __HIP_MEMORY_SCOPE_AGENT);
  } else {
    if (tid == 0) {
      __hip_atomic_fetch_add(gctr + (blk >> 4) * 64, 1u, __ATOMIC_RELAXED, __HIP_MEMORY_SCOPE_AGENT);
      while (__hip_atomic_load(rel + blk * 32, __ATOMIC_RELAXED, __HIP_MEMORY_SCOPE_AGENT) < gen)
        __builtin_amdgcn_s_sleep(1);
    }
  }
  __syncthreads();
}

// ---------------------------------------------------------------- fused time loop (R13 + gh-half moved to phase A)
// Per step t:
//   phase A: stage s_cur -> sm_s; attn(t) / patch(t-1); then ALL blocks compute the
//            s-dependent GRU half (w_hh rows, threads sl>=8) into sm_g rows 24..47
//   barrier
//   phase B: stage r_cur; r-dependent GRU half (threads sl<8, rows 0..23); elementwise
//            (gig/b_hh slices cached in LDS pre-loop; sprev read from sm_s)
//   barrier
__global__ __launch_bounds__(256, 1) void loop_k(
    const float* __restrict__ ktil, const float* __restrict__ cbn,
    const float* __restrict__ vt, const float* __restrict__ locg,
    float* __restrict__ sbuf, float* __restrict__ rbuf,
    const float* __restrict__ w_write, const float* __restrict__ b_write,
    const float* __restrict__ w_loc, const int* __restrict__ amask,
    float* __restrict__ patchbuf, float* __restrict__ locbuf,
    const float* __restrict__ gig, const float* __restrict__ w_ih,
    const float* __restrict__ w_hh, const float* __restrict__ b_hh,
    unsigned* __restrict__ bar) {
  __shared__ __align__(16) float sm_s[9216];    // gru s staging: 16 x 576 (prefetched in phase A)
  __shared__ __align__(16) float sm_rr[9216];   // gru r staging: 16 x 576 / patch act: 8 x 1152
  __shared__ __align__(16) float sm_g[832];     // gru results: 16 x 52 (rows 24..47 written in phase A)
  __shared__ __align__(16) float sm_sc[64];     // attn scores
  __shared__ __align__(16) float sm_val[192];   // patch results: 12 x 16
  __shared__ __align__(16) float sm_gig[384];   // per-block gig slice (constant over steps)
  __shared__ __align__(16) float sm_bhh[24];    // per-block b_hh slice
  __shared__ __align__(16) float wpl[12288];    // 48 KB patch weights (12 rows x 1024, swizzled)
  float* sm_act = sm_rr;

  const int blk = blockIdx.x, tid = threadIdx.x, lane = tid & 63;
  const bool is_attn = (blk < 64);
  const bool is_patch = (blk >= 64) && (blk < 224);
  unsigned nsync = 0;

  // ---- patch weights -> LDS (once), col-swizzled
  int p_rg = 0, p_bg = 0;
  if (is_patch) {
    const int g = blk - 64;
    p_bg = g & 3; p_rg = g >> 2;
    for (int idx = tid; idx < 3072; idx += 256) {     // 12 rows * 256 float4
      const int rho = idx >> 8, f4 = idx & 255;
      const int col = f4 << 2;
      const int cc2 = col >> 5, jj = (col >> 2) & 7;
      const int dcol = (cc2 << 5) | ((jj ^ (cc2 & 7)) << 2);
      const float* src = (rho < 10) ? (w_write + (long)(p_rg * 10 + rho) * 1024 + col)
                                    : (w_loc + (long)(rho - 10) * 1536 + col);
      *(float4*)(wpl + rho * 1024 + dcol) = *(const float4*)src;
    }
  }

  // ---- hoisted gru weights (all blocks): rows sl*3..sl*3+2 of 48  (96 persistent VGPRs)
  float4 wg[3][8];
  const int g_dg = blk & 63, g_bg = blk >> 6;
  {
    const int c = tid & 15, sl = tid >> 4;
#pragma unroll
    for (int i = 0; i < 3; ++i) {
      const int rho = sl * 3 + i;
      const float* wsrc;
      if (rho < 24) {
        const int g2 = rho >> 3, di = rho & 7;
        wsrc = w_ih + (long)(g2 * 512 + g_dg * 8 + di) * 1024 + c * 32;   // r-half cols [0,512)
      } else {
        const int rh = rho - 24, g2 = rh >> 3, di = rh & 7;
        wsrc = w_hh + (long)(g2 * 512 + g_dg * 8 + di) * 512 + c * 32;
      }
#pragma unroll
      for (int j = 0; j < 8; ++j) wg[i][j] = *(const float4*)(wsrc + 4 * j);
    }
  }
  // ---- cache gig / b_hh slices for the elementwise stage (constant across steps)
  if (tid < 128) {
    const int b_i = tid >> 3, di = tid & 7;
    const int b = g_bg * 16 + b_i, d = g_dg * 8 + di;
    sm_gig[tid * 3 + 0] = gig[(long)b * 1536 + d];
    sm_gig[tid * 3 + 1] = gig[(long)b * 1536 + 512 + d];
    sm_gig[tid * 3 + 2] = gig[(long)b * 1536 + 1024 + d];
  }
  if (tid < 8) {
    const int d = g_dg * 8 + tid;
    sm_bhh[tid * 3 + 0] = b_hh[d];
    sm_bhh[tid * 3 + 1] = b_hh[512 + d];
    sm_bhh[tid * 3 + 2] = b_hh[1024 + d];
  }
  __syncthreads();

  for (int t = 0; t <= TT; ++t) {
    const float* s_cur = sbuf + (long)t * (BB * DD);        // s_t (slot t)
    float* r_cur = rbuf + (long)t * (BB * DD);              // r_t (slot t)
    const float* r_prev = r_cur - BB * DD;                  // r_{t-1} (valid for t>=1)

    // ================= phase A =================
    // prefetch s staging for this block's gru batch-group
    if (t < TT) {
      const int sb2 = tid >> 4, ch = tid & 15;
      const int b = g_bg * 16 + sb2;
      const float* sp = s_cur + (long)b * DD + ch * 32;
      float* dsd = sm_s + sb2 * 576 + ch * 36;
#pragma unroll
      for (int jj = 0; jj < 8; ++jj)
        *(float4*)(dsd + 4 * jj) = *(const float4*)(sp + 4 * jj);
    }

    if (is_attn) {
      if (t < TT) {
        const int b = blk, wrp = tid >> 6;
        const float* sb = s_cur + (long)b * DD;
        const float4 sva = *(const float4*)(sb + lane * 8);
        const float4 svb = *(const float4*)(sb + lane * 8 + 4);
        for (int h8 = 0; h8 < 2; ++h8) {
          const float* kbase = ktil + ((long)(b * 64 + wrp * 16 + h8 * 8)) * DD + lane * 8;
          float4 ka[8], kb2[8];
#pragma unroll
          for (int i = 0; i < 8; ++i) {
            ka[i] = *(const float4*)(kbase + (long)i * DD);
            kb2[i] = *(const float4*)(kbase + (long)i * DD + 4);
          }
#pragma unroll
          for (int i = 0; i < 8; ++i) {
            float p = dot4(ka[i], sva) + dot4(kb2[i], svb);
#pragma unroll
            for (int off = 32; off; off >>= 1) p += __shfl_xor(p, off);
            if (lane == 0) {
              const int n = wrp * 16 + h8 * 8 + i;
              float sc = p + cbn[b * 64 + n];
              if (amask[b * 64 + n] == 0) sc = -1e9f;
              sm_sc[n] = sc;
            }
          }
        }
        __syncthreads();
        if (tid < 64) {
          const float v = sm_sc[tid];
          float m = v;
#pragma unroll
          for (int off = 32; off; off >>= 1) m = fmaxf(m, __shfl_xor(m, off));
          const float e = expf(v - m);
          float l2 = e;
#pragma unroll
          for (int off = 32; off; off >>= 1) l2 += __shfl_xor(l2, off);
          sm_sc[tid] = e / l2;
        }
        __syncthreads();
        // PV: thread covers d = 2*tid, 2*tid+1; 8-deep load groups (V L2-resident)
        float rx = 0.f, ry = 0.f;
        const float* vb = vt + (long)b * 64 * DD + (tid << 1);
        for (int n0 = 0; n0 < 64; n0 += 8) {
          float2 vv[8];
#pragma unroll
          for (int i = 0; i < 8; ++i)
            vv[i] = *(const float2*)(vb + (long)(n0 + i) * DD);
#pragma unroll
          for (int i = 0; i < 8; ++i) {
            const float a = sm_sc[n0 + i];
            rx = fmaf(a, vv[i].x, rx);
            ry = fmaf(a, vv[i].y, ry);
          }
        }
        cst(r_cur + (long)b * DD + (tid << 1), rx);
        cst(r_cur + (long)b * DD + (tid << 1) + 1, ry);
      }
    } else if (is_patch) {
      if (t >= 1) {
        const int c = tid & 31, sl = tid >> 5;
        const int tr = sl & 3, bgsub = sl >> 2;
        for (int h = 0; h < 2; ++h) {
          __syncthreads();
          {
            const int b_i8 = tid >> 5, l = tid & 31;
            const int b = p_bg * 16 + h * 8 + b_i8;
            const float* sp = s_cur + (long)b * DD + l * 16;
            const float* rp = r_prev + (long)b * DD + l * 16;
            float* dsd = sm_act + b_i8 * 1152 + (l >> 1) * 36 + (l & 1) * 16;
            float* drd = sm_act + b_i8 * 1152 + (16 + (l >> 1)) * 36 + (l & 1) * 16;
#pragma unroll
            for (int jj = 0; jj < 4; ++jj) {
              *(float4*)(dsd + 4 * jj) = *(const float4*)(sp + 4 * jj);
              *(float4*)(drd + 4 * jj) = *(const float4*)(rp + 4 * jj);
            }
          }
          __syncthreads();
          float4 wreg[3][8];
#pragma unroll
          for (int i = 0; i < 3; ++i) {
            const float* wrow = wpl + (tr * 3 + i) * 1024 + (c << 5);
#pragma unroll
            for (int j = 0; j < 8; ++j)
              wreg[i][j] = *(const float4*)(wrow + ((j ^ (c & 7)) << 2));
          }
          for (int bi = 0; bi < 4; ++bi) {
            const int bl = bgsub * 4 + bi;
            const int babs = p_bg * 16 + h * 8 + bl;
            const float* ap = sm_act + bl * 1152 + c * 36;
            float a0 = 0.f, a1 = 0.f, a2 = 0.f;
#pragma unroll
            for (int j = 0; j < 8; ++j) {
              const float4 av = *(const float4*)(ap + 4 * j);
              a0 += dot4(wreg[0][j], av);
              a1 += dot4(wreg[1][j], av);
              a2 += dot4(wreg[2][j], av);
            }
#pragma unroll
            for (int m = 1; m < 32; m <<= 1) {
              a0 += __shfl_xor(a0, m);
              a1 += __shfl_xor(a1, m);
              a2 += __shfl_xor(a2, m);
            }
            if (c == 0) {
              const int bslot = h * 8 + bl;
              const float av3[3] = {a0, a1, a2};
#pragma unroll
              for (int i = 0; i < 3; ++i) {
                const int rho = tr * 3 + i;
                float v = av3[i];
                if (rho >= 10) v += locg[babs * 2 + (rho - 10)];
                sm_val[rho * 16 + bslot] = v;
              }
            }
          }
        }
        __syncthreads();
        const int u = t - 1;
        if (tid < 160) {
          const int ri = tid >> 4, bl2 = tid & 15;
          const int row = p_rg * 10 + ri;
          const int b = p_bg * 16 + bl2;
          patchbuf[((long)u * 64 + b) * 400 + row] = sm_val[ri * 16 + bl2] + b_write[row];
        }
        if (p_rg == 0 && tid < 16) {
          const int b = p_bg * 16 + tid;
          const float lx = sm_val[160 + tid];
          const float ly = sm_val[176 + tid];
          const int jx = min(127, max(0, (int)rintf(0.5f * (tanhf(lx) + 1.f) * 127.f)));
          const int iy = min(127, max(0, (int)rintf(0.5f * (tanhf(ly) + 1.f) * 127.f)));
          locbuf[((long)u * 64 + b) * 2] = (float)jx;
          locbuf[((long)u * 64 + b) * 2 + 1] = (float)iy;
        }
      }
    }

    // ---- s-dependent GRU half (w_hh rows 24..47), computed in phase A by threads sl>=8
    if (t < TT) {
      __syncthreads();   // sm_s staged + phase-A LDS uses complete
      const int c = tid & 15, sl = tid >> 4;
      if (sl >= 8) {
        for (int bl = 0; bl < 16; ++bl) {
          const float* ap = sm_s + bl * 576 + c * 36;
          float a0 = 0.f, a1 = 0.f, a2 = 0.f;
#pragma unroll
          for (int j = 0; j < 8; ++j) {
            const float4 av = *(const float4*)(ap + 4 * j);
            a0 += dot4(wg[0][j], av);
            a1 += dot4(wg[1][j], av);
            a2 += dot4(wg[2][j], av);
          }
#pragma unroll
          for (int m = 1; m < 16; m <<= 1) {
            a0 += __shfl_xor(a0, m);
            a1 += __shfl_xor(a1, m);
            a2 += __shfl_xor(a2, m);
          }
          if (c == 0) {
            sm_g[bl * 52 + sl * 3 + 0] = a0;
            sm_g[bl * 52 + sl * 3 + 1] = a1;
            sm_g[bl * 52 + sl * 3 + 2] = a2;
          }
        }
      }
    }

    if (t == TT) break;          // last patch written; no in-kernel consumer

    grid_barrier(bar, ++nsync);

    // ================= phase B: gru(t) r-half + elementwise =================
    {
      float* s_nxt = sbuf + (long)(t + 1) * (BB * DD);
      const int c = tid & 15, sl = tid >> 4;
      // stage r for all 16 batches
      {
        const int sb2 = tid >> 4, ch = tid & 15;
        const int b = g_bg * 16 + sb2;
        const float* rp = r_cur + (long)b * DD + ch * 32;
        float* drd = sm_rr + sb2 * 576 + ch * 36;
#pragma unroll
        for (int jj = 0; jj < 8; ++jj)
          *(float4*)(drd + 4 * jj) = *(const float4*)(rp + 4 * jj);
      }
      __syncthreads();
      if (sl < 8) {
        for (int bl = 0; bl < 16; ++bl) {
          const float* ap = sm_rr + bl * 576 + c * 36;
          float a0 = 0.f, a1 = 0.f, a2 = 0.f;
#pragma unroll
          for (int j = 0; j < 8; ++j) {
            const float4 av = *(const float4*)(ap + 4 * j);
            a0 += dot4(wg[0][j], av);
            a1 += dot4(wg[1][j], av);
            a2 += dot4(wg[2][j], av);
          }
#pragma unroll
          for (int m = 1; m < 16; m <<= 1) {
            a0 += __shfl_xor(a0, m);
            a1 += __shfl_xor(a1, m);
            a2 += __shfl_xor(a2, m);
          }
          if (c == 0) {
            sm_g[bl * 52 + sl * 3 + 0] = a0;
            sm_g[bl * 52 + sl * 3 + 1] = a1;
            sm_g[bl * 52 + sl * 3 + 2] = a2;
          }
        }
      }
      __syncthreads();
      if (tid < 128) {
        const int b_i = tid >> 3, di = tid & 7;
        const int b = g_bg * 16 + b_i, d = g_dg * 8 + di;
        const float ir = sm_g[b_i * 52 + di]        + sm_gig[tid * 3 + 0];
        const float iz = sm_g[b_i * 52 + 8 + di]    + sm_gig[tid * 3 + 1];
        const float in = sm_g[b_i * 52 + 16 + di]   + sm_gig[tid * 3 + 2];
        const float hr = sm_g[b_i * 52 + 24 + di]   + sm_bhh[di * 3 + 0];
        const float hz = sm_g[b_i * 52 + 32 + di]   + sm_bhh[di * 3 + 1];
        const float hn = sm_g[b_i * 52 + 40 + di]   + sm_bhh[di * 3 + 2];
        const float rg2 = 1.f / (1.f + expf(-(ir + hr)));
        const float zg = 1.f / (1.f + expf(-(iz + hz)));
        const float ng = tanhf(in + rg2 * hn);
        const float sprev = sm_s[b_i * 576 + (d >> 5) * 36 + (d & 31)];
        cst(s_nxt + (long)b * DD + d, (1.f - zg) * ng + zg * sprev);
      }
    }

    grid_barrier(bar, ++nsync);
  }
}

// ---------------------------------------------------------------- canvas assembly (replaces zero_k + atomics)
__global__ __launch_bounds__(256) void canvas_k(const float* __restrict__ pb,
                                                const float* __restrict__ lb,
                                                float* __restrict__ canvas) {
  __shared__ float ch[16384];
  const int blk = blockIdx.x, tid = threadIdx.x;
  const int b = blk >> 4, c = blk & 15;
  for (int i = tid; i < 4096; i += 256)
    ((float4*)ch)[i] = make_float4(0.f, 0.f, 0.f, 0.f);
  __syncthreads();
  for (int u = 0; u < TT; ++u) {
    const int jx = (int)lb[((long)u * 64 + b) * 2];
    const int iy = (int)lb[((long)u * 64 + b) * 2 + 1];
    if (tid < 25) {
      const float v = pb[((long)u * 64 + b) * 400 + c * 25 + tid];
      const int ki = tid / 5, kj = tid % 5;
      const int y = iy + ki - 2, x = jx + kj - 2;
      if (y >= 0 && y < 128 && x >= 0 && x < 128) ch[y * 128 + x] += v;
    }
    __syncthreads();
  }
  float* dst = canvas + ((long)b * 16 + c) * 16384;
  for (int i = tid; i < 4096; i += 256)
    ((float4*)dst)[i] = ((float4*)ch)[i];
}

// ---------------------------------------------------------------- launch (4 kernels total)
extern "C" void kernel_launch(void* const* d_in, const int* in_sizes, int n_in,
                              void* d_out, int out_size, void* d_ws, size_t ws_size,
                              hipStream_t stream) {
  const float* tok     = (const float*)d_in[0];
  const float* grep    = (const float*)d_in[1];
  const int*   amask   = (const int*)d_in[2];
  const float* w_init  = (const float*)d_in[3];
  const float* b_init  = (const float*)d_in[4];
  const float* wq      = (const float*)d_in[5];
  const float* bq      = (const float*)d_in[6];
  const float* wk      = (const float*)d_in[7];
  const float* bk      = (const float*)d_in[8];
  const float* wv      = (const float*)d_in[9];
  const float* bv      = (const float*)d_in[10];
  const float* w_ih    = (const float*)d_in[11];
  const float* b_ih    = (const float*)d_in[12];
  const float* w_hh    = (const float*)d_in[13];
  const float* b_hh    = (const float*)d_in[14];
  const float* w_write = (const float*)d_in[15];
  const float* b_write = (const float*)d_in[16];
  const float* w_loc   = (const float*)d_in[17];
  const float* b_loc   = (const float*)d_in[18];
  float* canvas = (float*)d_out;

  float* ws = (float*)d_ws;
  float* ktil = ws;                      // 2,097,152
  float* vtw  = ktil + 2097152;          // 2,097,152 (vt)
  float* Aqk  = vtw + 2097152;           // 262,144 (layout keep)
  float* gig  = Aqk + 262144;            // 98,304
  float* cbn  = gig + 98304;             // 4,096
  float* sbuf = cbn + 4096;              // 33 slots * 32768 (s_0..s_32)
  float* rbuf = sbuf + 1081344;          // 32 slots * 32768 (r_0..r_31); ALSO aqkp scratch pre-loop
  float* locg = rbuf + 1048576;          // 128
  float* kqb  = locg + 128;              // 512
  float* wkbq = kqb + 512;               // 512 (unused)
  float* bqbk = wkbq + 512;              // 64 (pad, unused)
  unsigned* bar = (unsigned*)(bqbk + 64);// barrier region (16 group ctrs + 256 release words)
  float* patchbuf = (float*)(bar + 16384); // 32*64*400 = 819,200
  float* locbuf = patchbuf + 819200;     // 32*64*2 = 4,096
  float* aqkp = rbuf;                    // 4*262,144 Aqk split-K partials (dead until loop)

  // ONE setup launch: Aqk partials + kqb + cbn + gig + s0 + locg + barrier reset
  setup_k<<<180, 256, 0, stream>>>(wq, bq, wk, bk, tok, grep, w_ih, b_ih,
                                   w_init, b_init, w_loc, b_loc,
                                   kqb, cbn, gig, sbuf, locg, aqkp, bar);
  // ktil = tok @ Aqk^T + kqb (inline partial combine)  AND  vt = tok @ wv^T + bv
  dual2_k<<<dim3(32, 8, 2), 256, 0, stream>>>(tok, aqkp, kqb, ktil, wv, bv, vtw);
  // fused time loop
  loop_k<<<256, 256, 0, stream>>>(ktil, cbn, vtw, locg, sbuf, rbuf, w_write, b_write,
                                  w_loc, amask, patchbuf, locbuf, gig, w_ih, w_hh, b_hh, bar);
  // canvas assembly from deferred patches
  canvas_k<<<1024, 256, 0, stream>>>(patchbuf, locbuf, canvas);
}

// Round 15
// 1070.447 us; speedup vs baseline: 1.2059x; 1.2059x over previous
//
#include <hip/hip_runtime.h>

#define BB 64      // batch
#define DD 512     // d_model = d_state = d_att
#define TT 32      // steps

__device__ __forceinline__ float dot4(const float4 a, const float4 b) {
  return a.x * b.x + a.y * b.y + a.z * b.z + a.w * b.w;
}

// write-through (agent-scope) scalar store: recurrent-state writes visible at the LLC.
__device__ __forceinline__ void cst(float* p, float v) {
  __hip_atomic_store(p, v, __ATOMIC_RELAXED, __HIP_MEMORY_SCOPE_AGENT);
}

// ---------------------------------------------------------------- setup: everything before the loop, one launch
__global__ __launch_bounds__(256) void setup_k(
    const float* __restrict__ wq, const float* __restrict__ bq,
    const float* __restrict__ wk, const float* __restrict__ bk,
    const float* __restrict__ tok, const float* __restrict__ grep,
    const float* __restrict__ w_ih, const float* __restrict__ b_ih,
    const float* __restrict__ w_init, const float* __restrict__ b_init,
    const float* __restrict__ w_loc, const float* __restrict__ b_loc,
    float* __restrict__ kqb, float* __restrict__ cbn, float* __restrict__ gig,
    float* __restrict__ sbuf, float* __restrict__ locg,
    float* __restrict__ aqkp, unsigned* __restrict__ bar) {
  __shared__ __align__(16) float As[16][132];
  __shared__ __align__(16) float Bs[16][68];
  const int blk = blockIdx.x, tid = threadIdx.x;

  if (blk < 128) {
    // Aqk[e,m] split-K partial: C[e,m] = sum_{a in z-chunk} wq[a,e]*wk[a,m]
    const int tx = tid & 15, ty = tid >> 4;
    const int m0 = (blk & 3) * 128, n0 = ((blk >> 2) & 7) * 64, zz = blk >> 5;
    float acc[8][4];
#pragma unroll
    for (int i = 0; i < 8; ++i)
#pragma unroll
      for (int j = 0; j < 4; ++j) acc[i][j] = 0.f;
    for (int k0 = zz * 128; k0 < zz * 128 + 128; k0 += 16) {
      {
        const int kk = tid >> 4, mseg = tid & 15;
        const float* ap = wq + (long)(k0 + kk) * 512 + m0 + mseg * 8;
        *(float4*)&As[kk][mseg * 8] = *(const float4*)ap;
        *(float4*)&As[kk][mseg * 8 + 4] = *(const float4*)(ap + 4);
      }
      {
        const int kk = tid >> 4, nq = tid & 15;
        *(float4*)&Bs[kk][nq * 4] = *(const float4*)(wk + (long)(k0 + kk) * 512 + n0 + nq * 4);
      }
      __syncthreads();
#pragma unroll
      for (int kk = 0; kk < 16; ++kk) {
        const float4 a0 = *(const float4*)&As[kk][ty * 8];
        const float4 a1 = *(const float4*)&As[kk][ty * 8 + 4];
        const float4 b0 = *(const float4*)&Bs[kk][tx * 4];
        const float am[8] = {a0.x, a0.y, a0.z, a0.w, a1.x, a1.y, a1.z, a1.w};
#pragma unroll
        for (int i = 0; i < 8; ++i) {
          acc[i][0] += am[i] * b0.x; acc[i][1] += am[i] * b0.y;
          acc[i][2] += am[i] * b0.z; acc[i][3] += am[i] * b0.w;
        }
      }
      __syncthreads();
    }
    float* Ce = aqkp + (long)zz * 262144;
#pragma unroll
    for (int i = 0; i < 8; ++i) {
      const int m = m0 + ty * 8 + i;
      *(float4*)&Ce[(long)m * 512 + n0 + tx * 4] =
          make_float4(acc[i][0], acc[i][1], acc[i][2], acc[i][3]);
    }
  } else if (blk < 130) {
    const int d = (blk - 128) * 256 + tid;
    float s = 0.f;
    for (int e = 0; e < DD; ++e) s += wq[e * DD + d] * bk[e];
    kqb[d] = s;
  } else if (blk < 146) {
    // cbn[m] = tok[m,:].wkbq + bqbk ; wkbq/bqbk recomputed locally
    float* wkb = &As[0][0];            // 512 floats
    float* red = &Bs[0][0];            // 256 floats
    for (int k = tid; k < 512; k += 256) {
      float s = 0.f;
      for (int e = 0; e < DD; ++e) s += bq[e] * wk[e * DD + k];
      wkb[k] = s;
    }
    red[tid] = bq[tid] * bk[tid] + bq[tid + 256] * bk[tid + 256];
    __syncthreads();
    for (int s2 = 128; s2; s2 >>= 1) {
      if (tid < s2) red[tid] += red[tid + s2];
      __syncthreads();
    }
    const float bqbk = red[0];
    const int m = (blk - 130) * 256 + tid;
    const float* tr = tok + (long)m * 512;
    float acc = bqbk;
    for (int e = 0; e < 512; e += 8) {
      acc += dot4(*(const float4*)(tr + e), *(const float4*)(wkb + e));
      acc += dot4(*(const float4*)(tr + e + 4), *(const float4*)(wkb + e + 4));
    }
    cbn[m] = acc;
  } else if (blk < 170) {
    // gig[b,o] = grep[b,:].w_ih[o,512:1024] + b_ih[o]
    const int o = (blk - 146) * 64 + (tid & 63);
    const int b0 = (tid >> 6) * 16;
    float acc[16];
#pragma unroll
    for (int i = 0; i < 16; ++i) acc[i] = 0.f;
    const float* wr = w_ih + (long)o * 1024 + 512;
    for (int e = 0; e < 512; e += 4) {
      const float4 w4 = *(const float4*)(wr + e);
#pragma unroll
      for (int i = 0; i < 16; ++i)
        acc[i] += dot4(*(const float4*)(grep + (long)(b0 + i) * 512 + e), w4);
    }
    const float bi = b_ih[o];
#pragma unroll
    for (int i = 0; i < 16; ++i)
      gig[(long)(b0 + i) * 1536 + o] = acc[i] + bi;
  } else if (blk < 178) {
    // s0[b,d] = tanh(grep[b,:].w_init[d,:] + b_init[d]) -> sbuf slot 0
    const int d = (blk - 170) * 64 + (tid & 63);
    const int b0 = (tid >> 6) * 16;
    float acc[16];
#pragma unroll
    for (int i = 0; i < 16; ++i) acc[i] = 0.f;
    const float* wr = w_init + (long)d * 512;
    for (int e = 0; e < 512; e += 4) {
      const float4 w4 = *(const float4*)(wr + e);
#pragma unroll
      for (int i = 0; i < 16; ++i)
        acc[i] += dot4(*(const float4*)(grep + (long)(b0 + i) * 512 + e), w4);
    }
    const float bi = b_init[d];
#pragma unroll
    for (int i = 0; i < 16; ++i)
      sbuf[(long)(b0 + i) * 512 + d] = tanhf(acc[i] + bi);
  } else if (blk == 178) {
    // locg[b,j] = grep[b,:].w_loc[j,1024:1536] + b_loc[j]
    if (tid < 128) {
      const int b = tid >> 1, j = tid & 1;
      const float* wr = w_loc + (long)j * 1536 + 1024;
      const float* gr = grep + (long)b * 512;
      float acc = b_loc[j];
      for (int e = 0; e < 512; e += 4)
        acc += dot4(*(const float4*)(gr + e), *(const float4*)(wr + e));
      locg[b * 2 + j] = acc;
    }
  } else {
    if (tid < 16)
      __hip_atomic_store(bar + tid * 64, 0u, __ATOMIC_RELAXED, __HIP_MEMORY_SCOPE_AGENT);
    __hip_atomic_store(bar + 1024 + tid * 32, 0u, __ATOMIC_RELAXED, __HIP_MEMORY_SCOPE_AGENT);
  }
}

// ---------------------------------------------------------------- dual big GEMM with inline Aqk combine (2 blocks/CU)
__global__ __launch_bounds__(256) void dual2_k(
    const float* __restrict__ A, const float* __restrict__ aqkp,
    const float* __restrict__ bias0, float* __restrict__ C0,
    const float* __restrict__ B1, const float* __restrict__ bias1, float* __restrict__ C1) {
  __shared__ __align__(16) float As[16][132];
  __shared__ __align__(16) float Bs[16][68];
  const int tid = threadIdx.x;
  const int tx = tid & 15, ty = tid >> 4;
  const int m0 = blockIdx.x * 128, n0 = blockIdx.y * 64;
  const int z = blockIdx.z;
  const float* bias = z ? bias1 : bias0;
  float* C = z ? C1 : C0;
  float acc[8][4];
#pragma unroll
  for (int i = 0; i < 8; ++i)
#pragma unroll
    for (int j = 0; j < 4; ++j) acc[i][j] = 0.f;

  for (int k0 = 0; k0 < 512; k0 += 16) {
    {
      const int row = tid >> 1, half = tid & 1;
      const float* ap = A + (long)(m0 + row) * 512 + k0 + half * 8;
      const float4 a0 = *(const float4*)ap;
      const float4 a1 = *(const float4*)(ap + 4);
      const int kb = half * 8;
      As[kb + 0][row] = a0.x; As[kb + 1][row] = a0.y; As[kb + 2][row] = a0.z; As[kb + 3][row] = a0.w;
      As[kb + 4][row] = a1.x; As[kb + 5][row] = a1.y; As[kb + 6][row] = a1.z; As[kb + 7][row] = a1.w;
    }
    {
      const int n = tid >> 2, q = tid & 3;
      float4 b0;
      if (z == 0) {
        const float* pb = aqkp + (long)(n0 + n) * 512 + k0 + q * 4;
        const float4 p0 = *(const float4*)pb;
        const float4 p1 = *(const float4*)(pb + 262144);
        const float4 p2 = *(const float4*)(pb + 524288);
        const float4 p3 = *(const float4*)(pb + 786432);
        b0 = make_float4(p0.x + p1.x + p2.x + p3.x, p0.y + p1.y + p2.y + p3.y,
                         p0.z + p1.z + p2.z + p3.z, p0.w + p1.w + p2.w + p3.w);
      } else {
        b0 = *(const float4*)(B1 + (long)(n0 + n) * 512 + k0 + q * 4);
      }
      Bs[q * 4 + 0][n] = b0.x; Bs[q * 4 + 1][n] = b0.y; Bs[q * 4 + 2][n] = b0.z; Bs[q * 4 + 3][n] = b0.w;
    }
    __syncthreads();
#pragma unroll
    for (int kk = 0; kk < 16; ++kk) {
      const float4 a0 = *(const float4*)&As[kk][ty * 8];
      const float4 a1 = *(const float4*)&As[kk][ty * 8 + 4];
      const float4 b0 = *(const float4*)&Bs[kk][tx * 4];
      const float am[8] = {a0.x, a0.y, a0.z, a0.w, a1.x, a1.y, a1.z, a1.w};
#pragma unroll
      for (int i = 0; i < 8; ++i) {
        acc[i][0] += am[i] * b0.x; acc[i][1] += am[i] * b0.y;
        acc[i][2] += am[i] * b0.z; acc[i][3] += am[i] * b0.w;
      }
    }
    __syncthreads();
  }
  const float4 bvv = *(const float4*)(bias + n0 + tx * 4);
#pragma unroll
  for (int i = 0; i < 8; ++i) {
    const int m = m0 + ty * 8 + i;
    float4 v = make_float4(acc[i][0] + bvv.x, acc[i][1] + bvv.y, acc[i][2] + bvv.z, acc[i][3] + bvv.w);
    *(float4*)&C[(long)m * 512 + n0 + tx * 4] = v;
  }
}

// ---------------------------------------------------------------- two-level grid barrier (256 blocks), contention-free polling
__device__ __forceinline__ void grid_barrier(unsigned* __restrict__ bar, unsigned gen) {
  __syncthreads();   // vmcnt(0) drain: prior write-through stores have reached the LLC
  const int blk = blockIdx.x, tid = threadIdx.x;
  unsigned* gctr = bar;
  unsigned* rel = bar + 1024;
  if (blk == 0) {
    if (tid == 0)
      __hip_atomic_fetch_add(gctr, 1u, __ATOMIC_RELAXED, __HIP_MEMORY_SCOPE_AGENT);
    if (tid < 16) {
      while (__hip_atomic_load(gctr + tid * 64, __ATOMIC_RELAXED, __HIP_MEMORY_SCOPE_AGENT) < gen * 16u)
        __builtin_amdgcn_s_sleep(1);
    }
    __syncthreads();
    __hip_atomic_store(rel + tid * 32, gen, __ATOMIC_RELAXED, __HIP_MEMORY_SCOPE_AGENT);
  } else {
    if (tid == 0) {
      __hip_atomic_fetch_add(gctr + (blk >> 4) * 64, 1u, __ATOMIC_RELAXED, __HIP_MEMORY_SCOPE_AGENT);
      while (__hip_atomic_load(rel + blk * 32, __ATOMIC_RELAXED, __HIP_MEMORY_SCOPE_AGENT) < gen)
        __builtin_amdgcn_s_sleep(1);
    }
  }
  __syncthreads();
}

// ---------------------------------------------------------------- fused time loop (R8 structure + single-pass GRU + s-prefetch)
// 256 blocks, all barriered. Per step t:
//   phase A: all blocks prefetch s_cur (gru batch-group) -> sm_s;
//            blocks 0..63 attn(t); blocks 64..223 patch(t-1) -> patchbuf
//   barrier
//   phase B: stage r (single pass, 16 batches), gru dots, elementwise
//   barrier
// LDS ~124 KB (1 block/CU). sm_rr aliases patch's act staging.
__global__ __launch_bounds__(256, 1) void loop_k(
    const float* __restrict__ ktil, const float* __restrict__ cbn,
    const float* __restrict__ vt, const float* __restrict__ locg,
    float* __restrict__ sbuf, float* __restrict__ rbuf,
    const float* __restrict__ w_write, const float* __restrict__ b_write,
    const float* __restrict__ w_loc, const int* __restrict__ amask,
    float* __restrict__ patchbuf, float* __restrict__ locbuf,
    const float* __restrict__ gig, const float* __restrict__ w_ih,
    const float* __restrict__ w_hh, const float* __restrict__ b_hh,
    unsigned* __restrict__ bar) {
  __shared__ __align__(16) float sm_s[9216];    // gru s staging: 16 x 576 (prefetched in phase A)
  __shared__ __align__(16) float sm_rr[9216];   // gru r staging: 16 x 576 / patch act: 8 x 1152
  __shared__ __align__(16) float sm_g[832];     // gru results: 16 x 52
  __shared__ __align__(16) float sm_sc[64];     // attn scores
  __shared__ __align__(16) float sm_val[192];   // patch results: 12 x 16
  __shared__ __align__(16) float wpl[12288];    // 48 KB patch weights (12 rows x 1024, swizzled)
  float* sm_act = sm_rr;

  const int blk = blockIdx.x, tid = threadIdx.x, lane = tid & 63;
  const bool is_attn = (blk < 64);
  const bool is_patch = (blk >= 64) && (blk < 224);
  unsigned nsync = 0;

  // ---- patch weights -> LDS (once), col-swizzled
  int p_rg = 0, p_bg = 0;
  if (is_patch) {
    const int g = blk - 64;
    p_bg = g & 3; p_rg = g >> 2;
    for (int idx = tid; idx < 3072; idx += 256) {     // 12 rows * 256 float4
      const int rho = idx >> 8, f4 = idx & 255;
      const int col = f4 << 2;
      const int cc2 = col >> 5, jj = (col >> 2) & 7;
      const int dcol = (cc2 << 5) | ((jj ^ (cc2 & 7)) << 2);
      const float* src = (rho < 10) ? (w_write + (long)(p_rg * 10 + rho) * 1024 + col)
                                    : (w_loc + (long)(rho - 10) * 1536 + col);
      *(float4*)(wpl + rho * 1024 + dcol) = *(const float4*)src;
    }
  }

  // ---- hoisted gru weights (all blocks): rows sl*3..sl*3+2 of 48  (96 persistent VGPRs)
  float4 wg[3][8];
  const int g_dg = blk & 63, g_bg = blk >> 6;
  {
    const int c = tid & 15, sl = tid >> 4;
#pragma unroll
    for (int i = 0; i < 3; ++i) {
      const int rho = sl * 3 + i;
      const float* wsrc;
      if (rho < 24) {
        const int g2 = rho >> 3, di = rho & 7;
        wsrc = w_ih + (long)(g2 * 512 + g_dg * 8 + di) * 1024 + c * 32;   // r-half cols [0,512)
      } else {
        const int rh = rho - 24, g2 = rh >> 3, di = rh & 7;
        wsrc = w_hh + (long)(g2 * 512 + g_dg * 8 + di) * 512 + c * 32;
      }
#pragma unroll
      for (int j = 0; j < 8; ++j) wg[i][j] = *(const float4*)(wsrc + 4 * j);
    }
  }
  __syncthreads();

  for (int t = 0; t <= TT; ++t) {
    const float* s_cur = sbuf + (long)t * (BB * DD);        // s_t (slot t)
    float* r_cur = rbuf + (long)t * (BB * DD);              // r_t (slot t)
    const float* r_prev = r_cur - BB * DD;                  // r_{t-1} (valid for t>=1)

    // ================= phase A =================
    // prefetch s staging for this block's gru batch-group (consumed in phase B after barrier)
    if (t < TT) {
      const int sb2 = tid >> 4, ch = tid & 15;
      const int b = g_bg * 16 + sb2;
      const float* sp = s_cur + (long)b * DD + ch * 32;
      float* dsd = sm_s + sb2 * 576 + ch * 36;
#pragma unroll
      for (int jj = 0; jj < 8; ++jj)
        *(float4*)(dsd + 4 * jj) = *(const float4*)(sp + 4 * jj);
    }

    if (is_attn) {
      if (t < TT) {
        const int b = blk, wrp = tid >> 6;
        const float* sb = s_cur + (long)b * DD;
        const float4 sva = *(const float4*)(sb + lane * 8);
        const float4 svb = *(const float4*)(sb + lane * 8 + 4);
        for (int h8 = 0; h8 < 2; ++h8) {
          const float* kbase = ktil + ((long)(b * 64 + wrp * 16 + h8 * 8)) * DD + lane * 8;
          float4 ka[8], kb2[8];
#pragma unroll
          for (int i = 0; i < 8; ++i) {
            ka[i] = *(const float4*)(kbase + (long)i * DD);
            kb2[i] = *(const float4*)(kbase + (long)i * DD + 4);
          }
#pragma unroll
          for (int i = 0; i < 8; ++i) {
            float p = dot4(ka[i], sva) + dot4(kb2[i], svb);
#pragma unroll
            for (int off = 32; off; off >>= 1) p += __shfl_xor(p, off);
            if (lane == 0) {
              const int n = wrp * 16 + h8 * 8 + i;
              float sc = p + cbn[b * 64 + n];
              if (amask[b * 64 + n] == 0) sc = -1e9f;
              sm_sc[n] = sc;
            }
          }
        }
        __syncthreads();
        if (tid < 64) {
          const float v = sm_sc[tid];
          float m = v;
#pragma unroll
          for (int off = 32; off; off >>= 1) m = fmaxf(m, __shfl_xor(m, off));
          const float e = expf(v - m);
          float l2 = e;
#pragma unroll
          for (int off = 32; off; off >>= 1) l2 += __shfl_xor(l2, off);
          sm_sc[tid] = e / l2;
        }
        __syncthreads();
        // PV: thread covers d = 2*tid, 2*tid+1; 8-deep load groups (V L2-resident)
        float rx = 0.f, ry = 0.f;
        const float* vb = vt + (long)b * 64 * DD + (tid << 1);
        for (int n0 = 0; n0 < 64; n0 += 8) {
          float2 vv[8];
#pragma unroll
          for (int i = 0; i < 8; ++i)
            vv[i] = *(const float2*)(vb + (long)(n0 + i) * DD);
#pragma unroll
          for (int i = 0; i < 8; ++i) {
            const float a = sm_sc[n0 + i];
            rx = fmaf(a, vv[i].x, rx);
            ry = fmaf(a, vv[i].y, ry);
          }
        }
        cst(r_cur + (long)b * DD + (tid << 1), rx);
        cst(r_cur + (long)b * DD + (tid << 1) + 1, ry);
      }
    } else if (is_patch) {
      if (t >= 1) {
        const int c = tid & 31, sl = tid >> 5;
        const int tr = sl & 3, bgsub = sl >> 2;
        for (int h = 0; h < 2; ++h) {
          __syncthreads();
          {
            const int b_i8 = tid >> 5, l = tid & 31;
            const int b = p_bg * 16 + h * 8 + b_i8;
            const float* sp = s_cur + (long)b * DD + l * 16;
            const float* rp = r_prev + (long)b * DD + l * 16;
            float* dsd = sm_act + b_i8 * 1152 + (l >> 1) * 36 + (l & 1) * 16;
            float* drd = sm_act + b_i8 * 1152 + (16 + (l >> 1)) * 36 + (l & 1) * 16;
#pragma unroll
            for (int jj = 0; jj < 4; ++jj) {
              *(float4*)(dsd + 4 * jj) = *(const float4*)(sp + 4 * jj);
              *(float4*)(drd + 4 * jj) = *(const float4*)(rp + 4 * jj);
            }
          }
          __syncthreads();
          float4 wreg[3][8];
#pragma unroll
          for (int i = 0; i < 3; ++i) {
            const float* wrow = wpl + (tr * 3 + i) * 1024 + (c << 5);
#pragma unroll
            for (int j = 0; j < 8; ++j)
              wreg[i][j] = *(const float4*)(wrow + ((j ^ (c & 7)) << 2));
          }
          for (int bi = 0; bi < 4; ++bi) {
            const int bl = bgsub * 4 + bi;
            const int babs = p_bg * 16 + h * 8 + bl;
            const float* ap = sm_act + bl * 1152 + c * 36;
            float a0 = 0.f, a1 = 0.f, a2 = 0.f;
#pragma unroll
            for (int j = 0; j < 8; ++j) {
              const float4 av = *(const float4*)(ap + 4 * j);
              a0 += dot4(wreg[0][j], av);
              a1 += dot4(wreg[1][j], av);
              a2 += dot4(wreg[2][j], av);
            }
#pragma unroll
            for (int m = 1; m < 32; m <<= 1) {
              a0 += __shfl_xor(a0, m);
              a1 += __shfl_xor(a1, m);
              a2 += __shfl_xor(a2, m);
            }
            if (c == 0) {
              const int bslot = h * 8 + bl;
              const float av3[3] = {a0, a1, a2};
#pragma unroll
              for (int i = 0; i < 3; ++i) {
                const int rho = tr * 3 + i;
                float v = av3[i];
                if (rho >= 10) v += locg[babs * 2 + (rho - 10)];
                sm_val[rho * 16 + bslot] = v;
              }
            }
          }
        }
        __syncthreads();
        const int u = t - 1;
        if (tid < 160) {
          const int ri = tid >> 4, bl2 = tid & 15;
          const int row = p_rg * 10 + ri;
          const int b = p_bg * 16 + bl2;
          patchbuf[((long)u * 64 + b) * 400 + row] = sm_val[ri * 16 + bl2] + b_write[row];
        }
        if (p_rg == 0 && tid < 16) {
          const int b = p_bg * 16 + tid;
          const float lx = sm_val[160 + tid];
          const float ly = sm_val[176 + tid];
          const int jx = min(127, max(0, (int)rintf(0.5f * (tanhf(lx) + 1.f) * 127.f)));
          const int iy = min(127, max(0, (int)rintf(0.5f * (tanhf(ly) + 1.f) * 127.f)));
          locbuf[((long)u * 64 + b) * 2] = (float)jx;
          locbuf[((long)u * 64 + b) * 2 + 1] = (float)iy;
        }
      }
    }

    if (t == TT) break;          // last patch written; no in-kernel consumer

    grid_barrier(bar, ++nsync);

    // ================= phase B: gru(t), single staging pass =================
    {
      float* s_nxt = sbuf + (long)(t + 1) * (BB * DD);
      const int c = tid & 15, sl = tid >> 4;
      // stage r for all 16 batches (s already in sm_s from phase A)
      {
        const int sb2 = tid >> 4, ch = tid & 15;
        const int b = g_bg * 16 + sb2;
        const float* rp = r_cur + (long)b * DD + ch * 32;
        float* drd = sm_rr + sb2 * 576 + ch * 36;
#pragma unroll
        for (int jj = 0; jj < 8; ++jj)
          *(float4*)(drd + 4 * jj) = *(const float4*)(rp + 4 * jj);
      }
      __syncthreads();
      const float* base = (sl < 8) ? sm_rr : sm_s;
      for (int bl = 0; bl < 16; ++bl) {
        const float* ap = base + bl * 576 + c * 36;
        float a0 = 0.f, a1 = 0.f, a2 = 0.f;
#pragma unroll
        for (int j = 0; j < 8; ++j) {
          const float4 av = *(const float4*)(ap + 4 * j);
          a0 += dot4(wg[0][j], av);
          a1 += dot4(wg[1][j], av);
          a2 += dot4(wg[2][j], av);
        }
#pragma unroll
        for (int m = 1; m < 16; m <<= 1) {
          a0 += __shfl_xor(a0, m);
          a1 += __shfl_xor(a1, m);
          a2 += __shfl_xor(a2, m);
        }
        if (c == 0) {
          sm_g[bl * 52 + sl * 3 + 0] = a0;
          sm_g[bl * 52 + sl * 3 + 1] = a1;
          sm_g[bl * 52 + sl * 3 + 2] = a2;
        }
      }
      __syncthreads();
      if (tid < 128) {
        const int b_i = tid >> 3, di = tid & 7;
        const int b = g_bg * 16 + b_i, d = g_dg * 8 + di;
        const float ir = sm_g[b_i * 52 + di]        + gig[b * 1536 + d];
        const float iz = sm_g[b_i * 52 + 8 + di]    + gig[b * 1536 + 512 + d];
        const float in = sm_g[b_i * 52 + 16 + di]   + gig[b * 1536 + 1024 + d];
        const float hr = sm_g[b_i * 52 + 24 + di]   + b_hh[d];
        const float hz = sm_g[b_i * 52 + 32 + di]   + b_hh[512 + d];
        const float hn = sm_g[b_i * 52 + 40 + di]   + b_hh[1024 + d];
        const float rg2 = 1.f / (1.f + expf(-(ir + hr)));
        const float zg = 1.f / (1.f + expf(-(iz + hz)));
        const float ng = tanhf(in + rg2 * hn);
        const float sprev = s_cur[(long)b * DD + d];
        cst(s_nxt + (long)b * DD + d, (1.f - zg) * ng + zg * sprev);
      }
    }

    grid_barrier(bar, ++nsync);
  }
}

// ---------------------------------------------------------------- canvas assembly (replaces zero_k + atomics)
__global__ __launch_bounds__(256) void canvas_k(const float* __restrict__ pb,
                                                const float* __restrict__ lb,
                                                float* __restrict__ canvas) {
  __shared__ float ch[16384];
  const int blk = blockIdx.x, tid = threadIdx.x;
  const int b = blk >> 4, c = blk & 15;
  for (int i = tid; i < 4096; i += 256)
    ((float4*)ch)[i] = make_float4(0.f, 0.f, 0.f, 0.f);
  __syncthreads();
  for (int u = 0; u < TT; ++u) {
    const int jx = (int)lb[((long)u * 64 + b) * 2];
    const int iy = (int)lb[((long)u * 64 + b) * 2 + 1];
    if (tid < 25) {
      const float v = pb[((long)u * 64 + b) * 400 + c * 25 + tid];
      const int ki = tid / 5, kj = tid % 5;
      const int y = iy + ki - 2, x = jx + kj - 2;
      if (y >= 0 && y < 128 && x >= 0 && x < 128) ch[y * 128 + x] += v;
    }
    __syncthreads();
  }
  float* dst = canvas + ((long)b * 16 + c) * 16384;
  for (int i = tid; i < 4096; i += 256)
    ((float4*)dst)[i] = ((float4*)ch)[i];
}

// ---------------------------------------------------------------- launch (4 kernels total)
extern "C" void kernel_launch(void* const* d_in, const int* in_sizes, int n_in,
                              void* d_out, int out_size, void* d_ws, size_t ws_size,
                              hipStream_t stream) {
  const float* tok     = (const float*)d_in[0];
  const float* grep    = (const float*)d_in[1];
  const int*   amask   = (const int*)d_in[2];
  const float* w_init  = (const float*)d_in[3];
  const float* b_init  = (const float*)d_in[4];
  const float* wq      = (const float*)d_in[5];
  const float* bq      = (const float*)d_in[6];
  const float* wk      = (const float*)d_in[7];
  const float* bk      = (const float*)d_in[8];
  const float* wv      = (const float*)d_in[9];
  const float* bv      = (const float*)d_in[10];
  const float* w_ih    = (const float*)d_in[11];
  const float* b_ih    = (const float*)d_in[12];
  const float* w_hh    = (const float*)d_in[13];
  const float* b_hh    = (const float*)d_in[14];
  const float* w_write = (const float*)d_in[15];
  const float* b_write = (const float*)d_in[16];
  const float* w_loc   = (const float*)d_in[17];
  const float* b_loc   = (const float*)d_in[18];
  float* canvas = (float*)d_out;

  float* ws = (float*)d_ws;
  float* ktil = ws;                      // 2,097,152
  float* vtw  = ktil + 2097152;          // 2,097,152 (vt)
  float* Aqk  = vtw + 2097152;           // 262,144 (layout keep)
  float* gig  = Aqk + 262144;            // 98,304
  float* cbn  = gig + 98304;             // 4,096
  float* sbuf = cbn + 4096;              // 33 slots * 32768 (s_0..s_32)
  float* rbuf = sbuf + 1081344;          // 32 slots * 32768 (r_0..r_31); ALSO aqkp scratch pre-loop
  float* locg = rbuf + 1048576;          // 128
  float* kqb  = locg + 128;              // 512
  float* wkbq = kqb + 512;               // 512 (unused)
  float* bqbk = wkbq + 512;              // 64 (pad, unused)
  unsigned* bar = (unsigned*)(bqbk + 64);// barrier region (16 group ctrs + 256 release words)
  float* patchbuf = (float*)(bar + 16384); // 32*64*400 = 819,200
  float* locbuf = patchbuf + 819200;     // 32*64*2 = 4,096
  float* aqkp = rbuf;                    // 4*262,144 Aqk split-K partials (dead until loop)

  // ONE setup launch: Aqk partials + kqb + cbn + gig + s0 + locg + barrier reset
  setup_k<<<180, 256, 0, stream>>>(wq, bq, wk, bk, tok, grep, w_ih, b_ih,
                                   w_init, b_init, w_loc, b_loc,
                                   kqb, cbn, gig, sbuf, locg, aqkp, bar);
  // ktil = tok @ Aqk^T + kqb (inline partial combine)  AND  vt = tok @ wv^T + bv
  dual2_k<<<dim3(32, 8, 2), 256, 0, stream>>>(tok, aqkp, kqb, ktil, wv, bv, vtw);
  // fused time loop
  loop_k<<<256, 256, 0, stream>>>(ktil, cbn, vtw, locg, sbuf, rbuf, w_write, b_write,
                                  w_loc, amask, patchbuf, locbuf, gig, w_ih, w_hh, b_hh, bar);
  // canvas assembly from deferred patches
  canvas_k<<<1024, 256, 0, stream>>>(patchbuf, locbuf, canvas);
}